// Round 1
// baseline (16.774 us; speedup 1.0000x reference)
//
#include <hip/hip_runtime.h>
#include <hip/hip_bf16.h>

#define N_DIMS 128

// ---------------------------------------------------------------------------
// Kernel 1: per-node projection + index-width detection.
//   tsrc[n] = h[n] . Wsrc[c]            (c = 0..2)
//   tdst[n] = h[n] . Wdst[c] + b[c]
// One wave (64 lanes) per node; lane i holds h[n][2i..2i+1] as float2,
// 6 dot products reduced with __shfl_xor over the 64-lane wave.
// Block 0 additionally probes src's odd 32-bit words: if all zero the
// buffer is int64 (values < 10^4 => high word == 0), flag = 1 (shift),
// else int32, flag = 0.
// ---------------------------------------------------------------------------
__global__ __launch_bounds__(256) void hetero_proj_detect(
    const float* __restrict__ h, const float* __restrict__ W,
    const float* __restrict__ b, const unsigned int* __restrict__ src32,
    float4* __restrict__ tsrc, float4* __restrict__ tdst,
    int* __restrict__ flag, int n_nodes, int n_edges) {
  if (blockIdx.x == 0) {
    __shared__ int nz;
    if (threadIdx.x == 0) nz = 0;
    __syncthreads();
    int samples = n_edges < 4096 ? n_edges : 4096;
    int local = 0;
    for (int i = threadIdx.x; i < samples; i += 256)
      local |= (src32[2 * i + 1] != 0u) ? 1 : 0;
    if (local) nz = 1;
    __syncthreads();
    if (threadIdx.x == 0) flag[0] = nz ? 0 : 1;  // 1 => int64 layout
  }

  int gid  = blockIdx.x * 256 + threadIdx.x;
  int node = gid >> 6;
  int lane = threadIdx.x & 63;
  if (node >= n_nodes) return;

  float2 hv = *reinterpret_cast<const float2*>(h + (size_t)node * N_DIMS + lane * 2);

  float acc[6];
#pragma unroll
  for (int c = 0; c < 3; ++c) {
    // W row-major (3, 256): Wsrc[c][d] = W[c*256 + d], Wdst[c][d] = W[c*256 + 128 + d]
    float2 ws = *reinterpret_cast<const float2*>(W + c * 256 + lane * 2);
    float2 wd = *reinterpret_cast<const float2*>(W + c * 256 + 128 + lane * 2);
    acc[c]     = hv.x * ws.x + hv.y * ws.y;
    acc[3 + c] = hv.x * wd.x + hv.y * wd.y;
  }

#pragma unroll
  for (int off = 32; off >= 1; off >>= 1) {
#pragma unroll
    for (int k = 0; k < 6; ++k) acc[k] += __shfl_xor(acc[k], off, 64);
  }

  if (lane == 0) {
    tsrc[node] = make_float4(acc[0], acc[1], acc[2], 0.f);
    tdst[node] = make_float4(acc[3] + b[0], acc[4] + b[1], acc[5] + b[2], 0.f);
  }
}

// ---------------------------------------------------------------------------
// Kernel 2: per-edge gather-add.
//   out[e][c] = tsrc[src[e]][c] + tdst[dst[e]][c]
// Index fetch is branch-free for both int32/int64: word index = e << shift
// (little-endian low word of an int64 < 2^32 IS the value).
// Tables (2 x 160 KB) stay resident in L2; only indices + output hit HBM.
// ---------------------------------------------------------------------------
__global__ __launch_bounds__(256) void hetero_gather(
    const unsigned int* __restrict__ src32, const unsigned int* __restrict__ dst32,
    const float4* __restrict__ tsrc, const float4* __restrict__ tdst,
    float* __restrict__ out, int n_edges, const int* __restrict__ flag) {
  int e = blockIdx.x * 256 + threadIdx.x;
  if (e >= n_edges) return;
  int shift = flag[0];
  unsigned int s = src32[(size_t)e << shift];
  unsigned int d = dst32[(size_t)e << shift];
  float4 a = tsrc[s];
  float4 c = tdst[d];
  size_t o = (size_t)e * 3;
  out[o + 0] = a.x + c.x;
  out[o + 1] = a.y + c.y;
  out[o + 2] = a.z + c.z;
}

extern "C" void kernel_launch(void* const* d_in, const int* in_sizes, int n_in,
                              void* d_out, int out_size, void* d_ws, size_t ws_size,
                              hipStream_t stream) {
  const float*        h     = (const float*)d_in[0];
  const unsigned int* src32 = (const unsigned int*)d_in[1];
  const unsigned int* dst32 = (const unsigned int*)d_in[2];
  const float*        W     = (const float*)d_in[3];
  const float*        b     = (const float*)d_in[4];
  float*              out   = (float*)d_out;

  const int n_nodes = in_sizes[0] / N_DIMS;   // 10000
  const int n_edges = in_sizes[1];            // 500000

  char* ws = (char*)d_ws;
  float4* tsrc = (float4*)(ws);
  float4* tdst = (float4*)(ws + (size_t)n_nodes * sizeof(float4));
  int*    flag = (int*)(ws + 2 * (size_t)n_nodes * sizeof(float4));

  int proj_blocks = (n_nodes * 64 + 255) / 256;   // one wave per node
  hetero_proj_detect<<<proj_blocks, 256, 0, stream>>>(
      h, W, b, src32, tsrc, tdst, flag, n_nodes, n_edges);

  int gather_blocks = (n_edges + 255) / 256;
  hetero_gather<<<gather_blocks, 256, 0, stream>>>(
      src32, dst32, tsrc, tdst, out, n_edges, flag);
}